// Round 3
// baseline (699.719 us; speedup 1.0000x reference)
//
#include <hip/hip_runtime.h>

// ChebyshevKAN on MI355X (gfx950).
// Reformulation: einsum(bid,oid->bo) + x@base_w.T  ==  Xaug @ W^T with
//   Xaug[b, i*6+d] = T_{d+1}(tanh(x_i))  (d=0..4),  Xaug[b, i*6+5] = x_i
//   W[o,    i*6+d] = coeff[o,i,d+1]      (d=0..4),  W[o,    i*6+5] = base_w[o,i]
// T0==1 slice folds into bias:  bias'[o] = bias[o] + sum_i coeff[o,i,0].
//
// R8 == R7 resubmit (R7 bench died at container level; ledger re-audited,
// no kernel-side hang/fault found -- see session journal).
// R7: R6's 8-phase gemm1 measured MfmaUtil 34% == serial {reads -> lgkm(0) ->
// MFMA} per phase (reads issued in the same phase they're consumed). Fix =
// derived-waits read-ahead: frag ds_reads for phase p+1 issue in block p;
// before MFMA p wait counted lgkmcnt(N_new) draining only the older reads.
// Ledger (per iter, tiles kt->buf0, kt+1->buf1; stage=4 loads each):
//   reads ahead: m8:b(buf0,k0)  m1:a(0,mh0,k0)[in-blk]+a(0,mh0,k1)+b(0,k1)
//                m2:a(0,mh1,k0) m3:a(0,mh1,k1) m4:b(1,k0)
//                m5:a(1,mh0,k0)[in-blk]+a(1,mh0,k1)+b(1,k1) m6:a(1,mh1,k0)
//                m7:a(1,mh1,k1)
//   stages: m1:A(kt+1)->buf1  m3:B(kt+2)->buf0  m5:A(kt+2)->buf0
//           m7:B(kt+3)->buf1   (each >=1 barrier after last read of region)
//   vmcnt:  m3:8 (drain B1,gates m4 b-read)   m4:4 (drain A1, gates m5 a)
//           m7:8 (drain B0new, gates m8 b)    m8:4 (drain A0new, gates m1 a)
//   lgkm:   m1:8 m2:4 m3:4 m4:4 m5:8 m6:4 m7:4 m8:4  (DS completes in-order;
//           m1/m5 pin their in-block a-reads first via sched_barrier(0))
// gemm2 is the R0-verified m97-style 64x128 kernel.

typedef __bf16 bf16x8 __attribute__((ext_vector_type(8)));
typedef float f32x4 __attribute__((ext_vector_type(4)));
typedef unsigned short u16x8 __attribute__((ext_vector_type(8)));

__device__ __forceinline__ unsigned short f2bf(float f) {
    unsigned int u = __float_as_uint(f);
    unsigned int r = (u + 0x7FFFu + ((u >> 16) & 1u)) >> 16;
    return (unsigned short)r;
}
__device__ __forceinline__ float bf2f(unsigned short b) {
    return __uint_as_float(((unsigned int)b) << 16);
}

__device__ __forceinline__ float fast_tanh(float x) {
    float a = fminf(fmaxf(x, -15.f), 15.f);
    float e = __expf(2.f * a);
    return 1.f - 2.f * __builtin_amdgcn_rcpf(e + 1.f);
}
__device__ __forceinline__ float fast_silu(float y) {
    float a = fminf(fmaxf(y, -30.f), 30.f);
    return y * __builtin_amdgcn_rcpf(1.f + __expf(-a));
}

__device__ __forceinline__ void cheb_pack(float s, unsigned short* o6) {
    float u  = fast_tanh(s);
    float T1 = u;
    float T2 = 2.f * u * u - 1.f;
    float T3 = 2.f * u * T2 - T1;
    float T4 = 2.f * u * T3 - T2;
    float T5 = 2.f * u * T4 - T3;
    o6[0] = f2bf(T1); o6[1] = f2bf(T2); o6[2] = f2bf(T3);
    o6[3] = f2bf(T4); o6[4] = f2bf(T5); o6[5] = f2bf(s);
}

__device__ __forceinline__ void load_lds16(const void* g, void* l) {
    __builtin_amdgcn_global_load_lds(
        (const __attribute__((address_space(1))) void*)g,
        (__attribute__((address_space(3))) void*)l, 16, 0, 0);
}

// ---------------- prep: weights [O,I,6]+[O,I] -> W[N=O, K=I*6] bf16 ----------
__global__ __launch_bounds__(256) void prep_w_kernel(
    const float* __restrict__ coeff, const float* __restrict__ base_w,
    unsigned short* __restrict__ W, int OI)
{
    int idx = blockIdx.x * 256 + threadIdx.x;
    if (idx >= OI) return;
    const float* c = coeff + (size_t)idx * 6;
    unsigned short w0 = f2bf(c[1]), w1 = f2bf(c[2]), w2 = f2bf(c[3]),
                   w3 = f2bf(c[4]), w4 = f2bf(c[5]), w5 = f2bf(base_w[idx]);
    unsigned int* d = (unsigned int*)(W + (size_t)idx * 6);
    d[0] = w0 | ((unsigned int)w1 << 16);
    d[1] = w2 | ((unsigned int)w3 << 16);
    d[2] = w4 | ((unsigned int)w5 << 16);
}

__global__ __launch_bounds__(256) void prep_bias_kernel(
    const float* __restrict__ coeff, const float* __restrict__ bias,
    float* __restrict__ bp, int I)
{
    int o = blockIdx.x, tid = threadIdx.x;
    float s = 0.f;
    for (int i = tid; i < I; i += 256) s += coeff[((size_t)o * I + i) * 6];
    #pragma unroll
    for (int off = 32; off > 0; off >>= 1) s += __shfl_down(s, off);
    __shared__ float red[4];
    int lane = tid & 63, wv = tid >> 6;
    if (lane == 0) red[wv] = s;
    __syncthreads();
    if (tid == 0) bp[o] = bias[o] + red[0] + red[1] + red[2] + red[3];
}

// ---------------- expand1: x[b,1024] -> Xaug[b,6144] bf16  (block per row) ---
__global__ __launch_bounds__(256) void expand1_kernel(
    const float* __restrict__ x, unsigned short* __restrict__ Xa)
{
    int b = blockIdx.x, tid = threadIdx.x;
    f32x4 xv = *(const f32x4*)(x + (size_t)b * 1024 + tid * 4);
    alignas(16) unsigned short ov[24];
    #pragma unroll
    for (int e = 0; e < 4; e++) cheb_pack(fast_tanh(xv[e]), ov + e * 6);
    u16x8* dst = (u16x8*)(Xa + (size_t)b * 6144 + tid * 24);
    const u16x8* src = (const u16x8*)ov;
    dst[0] = src[0]; dst[1] = src[1]; dst[2] = src[2];
}

// ------------- LN + SiLU + expand2 fused (block per row of 1024, h in bf16) --
__global__ __launch_bounds__(256) void ln_silu_expand_kernel(
    const unsigned short* __restrict__ H, const float* __restrict__ gamma,
    const float* __restrict__ beta, unsigned short* __restrict__ Xa)
{
    int b = blockIdx.x, tid = threadIdx.x;
    ushort4 hb = *(const ushort4*)(H + (size_t)b * 1024 + tid * 4);
    float hv[4] = { bf2f(hb.x), bf2f(hb.y), bf2f(hb.z), bf2f(hb.w) };
    float s1 = hv[0] + hv[1] + hv[2] + hv[3];
    float s2 = hv[0]*hv[0] + hv[1]*hv[1] + hv[2]*hv[2] + hv[3]*hv[3];
    #pragma unroll
    for (int off = 32; off > 0; off >>= 1) {
        s1 += __shfl_down(s1, off);
        s2 += __shfl_down(s2, off);
    }
    __shared__ float red[8];
    __shared__ float stats[2];
    int lane = tid & 63, wv = tid >> 6;
    if (lane == 0) { red[wv] = s1; red[4 + wv] = s2; }
    __syncthreads();
    if (tid == 0) {
        float t1 = red[0] + red[1] + red[2] + red[3];
        float t2 = red[4] + red[5] + red[6] + red[7];
        float mu = t1 * (1.f / 1024.f);
        float var = t2 * (1.f / 1024.f) - mu * mu;
        stats[0] = mu;
        stats[1] = rsqrtf(var + 1e-5f);
    }
    __syncthreads();
    float mu = stats[0], rs = stats[1];
    f32x4 g  = *(const f32x4*)(gamma + tid * 4);
    f32x4 bt = *(const f32x4*)(beta  + tid * 4);
    alignas(16) unsigned short ov[24];
    #pragma unroll
    for (int e = 0; e < 4; e++) {
        float y = (hv[e] - mu) * rs * g[e] + bt[e];
        cheb_pack(fast_silu(y), ov + e * 6);
    }
    u16x8* dst = (u16x8*)(Xa + (size_t)b * 6144 + tid * 24);
    const u16x8* src = (const u16x8*)ov;
    dst[0] = src[0]; dst[1] = src[1]; dst[2] = src[2];
}

// ============ gemm1: 256x256 8-phase read-ahead pipeline (bf16 out) =========
#define FENCE() asm volatile("" ::: "memory")
#define MIDB()  do { FENCE(); __builtin_amdgcn_s_barrier(); } while (0)
#define ENDB()  do { __builtin_amdgcn_s_setprio(0); FENCE(); \
                     __builtin_amdgcn_s_barrier(); FENCE(); } while (0)
#define LG0() do { asm volatile("s_waitcnt lgkmcnt(0)" ::: "memory"); \
                   __builtin_amdgcn_sched_barrier(0); } while (0)
#define LG4() do { asm volatile("s_waitcnt lgkmcnt(4)" ::: "memory"); \
                   __builtin_amdgcn_sched_barrier(0); } while (0)
#define LG8() do { asm volatile("s_waitcnt lgkmcnt(8)" ::: "memory"); \
                   __builtin_amdgcn_sched_barrier(0); } while (0)
#define VMC0() asm volatile("s_waitcnt vmcnt(0)" ::: "memory")
#define VMC4() asm volatile("s_waitcnt vmcnt(4)" ::: "memory")
#define VMC8() asm volatile("s_waitcnt vmcnt(8)" ::: "memory")
#define SB0()  __builtin_amdgcn_sched_barrier(0)

// 4 A-frags of (mh, one k-half)
#define RD_A4(DST, BASE, MH, CS) do { \
    _Pragma("unroll") \
    for (int mf = 0; mf < 4; ++mf) \
        DST[mf] = *(const bf16x8*)((BASE) + ((MH) * 64 + mf * 16) * 64 + (CS)); \
    } while (0)
// 4 B-frags at one k-half
#define RD_B4(DST, BASE, CS) do { \
    _Pragma("unroll") \
    for (int nf = 0; nf < 4; ++nf) \
        DST[nf] = *(const bf16x8*)((BASE) + (nf * 16) * 64 + (CS)); \
    } while (0)

#define QUAD(MH, AV, BV) do { \
    __builtin_amdgcn_s_setprio(1); \
    _Pragma("unroll") \
    for (int mf = 0; mf < 4; ++mf) \
        _Pragma("unroll") \
        for (int nf = 0; nf < 4; ++nf) \
            acc[MH][mf][nf] = __builtin_amdgcn_mfma_f32_16x16x32_bf16( \
                AV[mf], BV[nf], acc[MH][mf][nf], 0, 0, 0); \
    } while (0)

__global__ __launch_bounds__(512, 2) void gemm8_kernel(
    const unsigned short* __restrict__ A,   // [M,K] bf16 bits
    const unsigned short* __restrict__ Wt,  // [N,K] bf16 bits
    const float* __restrict__ bias,         // [N]
    unsigned short* __restrict__ Cout,      // [M,N] bf16
    int N, int K, int NMT)
{
    __shared__ __align__(16) unsigned short As[2 * 256 * 64];
    __shared__ __align__(16) unsigned short Bs[2 * 256 * 64];

    const int tid  = threadIdx.x;
    const int lane = tid & 63;
    const int wave = tid >> 6;
    const int wm   = wave >> 2;     // 0..1
    const int wn   = wave & 3;      // 0..3

    int wg = blockIdx.x;
    {
        const int nwg = gridDim.x;
        if ((nwg & 7) == 0) {
            const int cpx = nwg >> 3;
            wg = (wg & 7) * cpx + (wg >> 3);
        }
    }
    const int mt = wg % NMT;
    const int nt = wg / NMT;
    const size_t m0 = (size_t)mt * 256;
    const size_t n0 = (size_t)nt * 256;

    // staging lane offsets (chunk-XOR pre-swizzled global source, linear LDS)
    const int srow   = lane >> 3;
    const int schunk = (lane & 7) ^ (srow & 7);
    const unsigned short* Ag = A  + (m0 + srow) * (size_t)K + schunk * 8;
    const unsigned short* Bg = Wt + (n0 + srow) * (size_t)K + schunk * 8;

    // frag-read lane offsets (XOR de-swizzle on read)
    const int fr  = lane & 15;
    const int cg  = lane >> 4;
    const int fr7 = fr & 7;
    const int c0  = ((cg    ) ^ fr7) << 3;
    const int c1  = ((cg + 4) ^ fr7) << 3;

    const int NT = K >> 6;          // 64-wide K-tiles (even, >=4)

    const unsigned short* A0f = As + fr * 64 + (wm * 128) * 64;
    const unsigned short* A1f = A0f + 256 * 64;
    const unsigned short* B0f = Bs + fr * 64 + (wn * 64) * 64;
    const unsigned short* B1f = B0f + 256 * 64;

    auto stageA = [&](int kt, int bsel) {
        const unsigned short* g = Ag + kt * 64;
        unsigned short* l = As + bsel * (256 * 64);
        #pragma unroll
        for (int j = 0; j < 4; ++j) {
            const int u = wave * 4 + j;
            load_lds16(g + (size_t)(u * 8) * K, l + u * 512);
        }
    };
    auto stageB = [&](int kt, int bsel) {
        const unsigned short* g = Bg + kt * 64;
        unsigned short* l = Bs + bsel * (256 * 64);
        #pragma unroll
        for (int j = 0; j < 4; ++j) {
            const int u = wave * 4 + j;
            load_lds16(g + (size_t)(u * 8) * K, l + u * 512);
        }
    };

    f32x4 acc[2][4][4];
    #pragma unroll
    for (int mh = 0; mh < 2; ++mh)
        #pragma unroll
        for (int mf = 0; mf < 4; ++mf)
            #pragma unroll
            for (int nf = 0; nf < 4; ++nf)
                acc[mh][mf][nf] = f32x4{0.f, 0.f, 0.f, 0.f};

    bf16x8 aP[4], aQ[4], b0[4], b1[4];

    // prologue: stage T0 (B,A) + T1 (B); gate T0; pre-read b(T0,k0)
    stageB(0, 0); stageA(0, 0); stageB(1, 1);
    VMC4();                                   // drain B0,A0; B1 in flight
    MIDB(); FENCE();
    RD_B4(b0, B0f, c0);
    SB0();                                    // pin issue order vs m1 reads

    for (int kt = 0; kt < NT; kt += 2) {
        const bool st = (kt + 4) <= NT;

        // ---- m1: MFMA (buf0, mh0, k0) = aP x b0
        RD_A4(aP, A0f, 0, c0);                // in-block (gated by VMC4 @m8/prol)
        SB0();                                // aP must be oldest of this block
        RD_A4(aQ, A0f, 0, c1);
        RD_B4(b1, B0f, c1);
        stageA(kt + 1, 1);                    // buf1.A (old drained @m8 prev)
        MIDB(); LG8();                        // drain b0(prev) + aP
        QUAD(0, aP, b0); ENDB();

        // ---- m2: MFMA (buf0, mh0, k1) = aQ x b1
        RD_A4(aP, A0f, 1, c0);
        MIDB(); LG4();                        // drain aQ + b1
        QUAD(0, aQ, b1); ENDB();

        // ---- m3: MFMA (buf0, mh1, k0) = aP x b0
        RD_A4(aQ, A0f, 1, c1);
        if (st) { stageB(kt + 2, 0); VMC8(); }   // [B1,A1,B0n]=12 -> drain B1
        else    { VMC4(); }                      // [B1,A1]=8     -> drain B1
        MIDB(); LG4();                        // drain aP
        QUAD(1, aP, b0); ENDB();

        // ---- m4: MFMA (buf0, mh1, k1) = aQ x b1
        RD_B4(b0, B1f, c0);                   // ahead m5 (buf1.B gated @m3)
        if (st) VMC4(); else VMC0();          // drain A1 (gates m5 a-read)
        MIDB(); LG4();                        // drain aQ
        QUAD(1, aQ, b1); ENDB();

        // ---- m5: MFMA (buf1, mh0, k0) = aP x b0
        RD_A4(aP, A1f, 0, c0);                // in-block (gated by VMC @m4)
        SB0();
        RD_A4(aQ, A1f, 0, c1);
        RD_B4(b1, B1f, c1);
        if (st) stageA(kt + 2, 0);            // buf0.A (old drained @m4)
        MIDB(); LG8();                        // drain b0 + aP
        QUAD(0, aP, b0); ENDB();

        // ---- m6: MFMA (buf1, mh0, k1) = aQ x b1
        RD_A4(aP, A1f, 1, c0);
        MIDB(); LG4();                        // drain aQ + b1
        QUAD(0, aQ, b1); ENDB();

        // ---- m7: MFMA (buf1, mh1, k0) = aP x b0
        RD_A4(aQ, A1f, 1, c1);
        if (st) { stageB(kt + 3, 1); VMC8(); }   // [B0n,A0n,B1n]=12 -> drain B0n
        else    { VMC0(); }
        MIDB(); LG4();                        // drain aP
        QUAD(1, aP, b0); ENDB();

        // ---- m8: MFMA (buf1, mh1, k1) = aQ x b1
        if (st) { RD_B4(b0, B0f, c0); SB0(); VMC4(); }  // ahead next-m1; drain A0n
        else    { VMC0(); }
        MIDB();
        if (st) { LG4(); } else { LG0(); }    // drain aQ
        QUAD(1, aQ, b1); ENDB();
    }

    // C/D layout (verified): col = lane&15, row = (lane>>4)*4 + reg
    const size_t rbase0 = m0 + wm * 128 + ((lane >> 4) << 2);
    const int cb = lane & 15;
    int colg[4]; float bv[4];
    #pragma unroll
    for (int nf = 0; nf < 4; ++nf) {
        colg[nf] = (int)n0 + wn * 64 + nf * 16 + cb;
        bv[nf] = bias[colg[nf]];
    }
    #pragma unroll
    for (int mh = 0; mh < 2; ++mh)
        #pragma unroll
        for (int mf = 0; mf < 4; ++mf) {
            const size_t rg0 = rbase0 + mh * 64 + mf * 16;
            #pragma unroll
            for (int r = 0; r < 4; ++r) {
                const size_t rowoff = (rg0 + r) * (size_t)N;
                #pragma unroll
                for (int nf = 0; nf < 4; ++nf)
                    Cout[rowoff + colg[nf]] = f2bf(acc[mh][mf][nf][r] + bv[nf]);
            }
        }
}

// ============ gemm2: R0-verified m97-style BM=64 x 128 tile (f32 out) ========
__global__ __launch_bounds__(256, 4) void gemm_kernel(
    const unsigned short* __restrict__ A,   // [M,K] bf16 bits
    const unsigned short* __restrict__ Wt,  // [N,K] bf16 bits
    const float* __restrict__ bias,         // [N]
    float* __restrict__ Cout,               // [M,N] f32
    int N, int K)
{
    constexpr int BM = 64;
    constexpr int MI = BM / 32;
    __shared__ __align__(16) unsigned short As[BM * 64];
    __shared__ __align__(16) unsigned short Bs[128 * 64];
    const int tid  = threadIdx.x;
    const int lane = tid & 63;
    const int wave = tid >> 6;
    const int ntn  = N >> 7;

    int bkid = blockIdx.x;
    const int nm = gridDim.x / ntn;
    int mt, nt;
    if ((nm & 7) == 0) {
        const int mg = nm >> 3;
        const int s  = bkid >> 3;
        const int q  = s / ntn;
        mt = (bkid & 7) * mg + q;
        nt = s - q * ntn;
    } else {
        mt = bkid / ntn; nt = bkid % ntn;
    }
    const size_t m0 = (size_t)mt * BM;
    const size_t n0 = (size_t)nt << 7;

    const int wr = (wave >> 1) * (BM / 2);
    const int wc = (wave & 1) * 64;
    const int fr = lane & 15;
    const int cg = lane >> 4;
    const int srow = tid >> 3;
    const int schunk = (tid & 7) ^ (srow & 7);

    const int fr7 = fr & 7;
    const unsigned short* fA0 = As + (wr + fr) * 64 + ((cg    ) ^ fr7) * 8;
    const unsigned short* fA1 = As + (wr + fr) * 64 + ((cg + 4) ^ fr7) * 8;
    const unsigned short* fB0 = Bs + (wc + fr) * 64 + ((cg    ) ^ fr7) * 8;
    const unsigned short* fB1 = Bs + (wc + fr) * 64 + ((cg + 4) ^ fr7) * 8;

    const unsigned short* Agu = A  + m0 * (size_t)K;
    const unsigned short* Bgu = Wt + n0 * (size_t)K;
    const int loff = srow * K + schunk * 8;

    f32x4 acc[MI][4];
    #pragma unroll
    for (int i = 0; i < MI; i++)
        #pragma unroll
        for (int j = 0; j < 4; j++) acc[i][j] = f32x4{0.f, 0.f, 0.f, 0.f};

    for (int k0 = 0; k0 < K; k0 += 64) {
        const unsigned short* ak = Agu + k0;
        const unsigned short* bk = Bgu + k0;
        #pragma unroll
        for (int s = 0; s < BM / 32; ++s)
            load_lds16(ak + s * 32 * K + loff, &As[(s * 256 + wave * 64) * 8]);
        #pragma unroll
        for (int s = 0; s < 4; ++s)
            load_lds16(bk + s * 32 * K + loff, &Bs[(s * 256 + wave * 64) * 8]);
        __syncthreads();

        bf16x8 af[MI], bfr[4];
        #pragma unroll
        for (int i = 0; i < MI; i++) af[i]  = *(const bf16x8*)(fA0 + i * 1024);
        #pragma unroll
        for (int j = 0; j < 4; j++)  bfr[j] = *(const bf16x8*)(fB0 + j * 1024);
        #pragma unroll
        for (int i = 0; i < MI; i++)
            #pragma unroll
            for (int j = 0; j < 4; j++)
                acc[i][j] = __builtin_amdgcn_mfma_f32_16x16x32_bf16(
                    af[i], bfr[j], acc[i][j], 0, 0, 0);
        #pragma unroll
        for (int i = 0; i < MI; i++) af[i]  = *(const bf16x8*)(fA1 + i * 1024);
        #pragma unroll
        for (int j = 0; j < 4; j++)  bfr[j] = *(const bf16x8*)(fB1 + j * 1024);
        #pragma unroll
        for (int i = 0; i < MI; i++)
            #pragma unroll
            for (int j = 0; j < 4; j++)
                acc[i][j] = __builtin_amdgcn_mfma_f32_16x16x32_bf16(
                    af[i], bfr[j], acc[i][j], 0, 0, 0);
        __syncthreads();
    }

    const int rbase = wr + (lane >> 4) * 4;
    const int cbase = wc + (lane & 15);
    #pragma unroll
    for (int j = 0; j < 4; j++) {
        const int col = (int)n0 + cbase + j * 16;
        const float bv = bias[col];
        #pragma unroll
        for (int i = 0; i < MI; i++) {
            #pragma unroll
            for (int r = 0; r < 4; r++) {
                const size_t idx = (m0 + rbase + i * 16 + r) * N + col;
                Cout[idx] = acc[i][j][r] + bv;
            }
        }
    }
}

extern "C" void kernel_launch(void* const* d_in, const int* in_sizes, int n_in,
                              void* d_out, int out_size, void* d_ws, size_t ws_size,
                              hipStream_t stream)
{
    const float* x       = (const float*)d_in[0];
    const float* coeff1  = (const float*)d_in[1];
    const float* base_w1 = (const float*)d_in[2];
    const float* bias1   = (const float*)d_in[3];
    const float* gamma   = (const float*)d_in[4];
    const float* beta    = (const float*)d_in[5];
    const float* coeff2  = (const float*)d_in[6];
    const float* base_w2 = (const float*)d_in[7];
    const float* bias2   = (const float*)d_in[8];
    float* out = (float*)d_out;

    const int B = 16384, D0 = 1024, D1 = 1024, D2 = 512;
    const int K1 = D0 * 6, K2 = D1 * 6;   // 6144 each

    char* base = (char*)d_ws;
    size_t off = 0;
    unsigned short* W1 = (unsigned short*)(base + off); off += (size_t)D1 * K1 * 2;
    unsigned short* W2 = (unsigned short*)(base + off); off += (size_t)D2 * K2 * 2;
    float* b1p = (float*)(base + off); off += (size_t)D1 * 4;
    float* b2p = (float*)(base + off); off += (size_t)D2 * 4;
    off = (off + 255) & ~(size_t)255;

    size_t per_row = (size_t)K1 * 2 + (size_t)D1 * 2;   // 14336 B
    long long avail = (long long)ws_size - (long long)off;
    long long mcl = avail > 0 ? avail / (long long)per_row : 0;
    int Mc = (int)((mcl / 256) * 256);
    if (Mc < 256) Mc = 256;
    if (Mc > B) Mc = B;

    unsigned short* Xa = (unsigned short*)(base + off);
    unsigned short* h = (unsigned short*)(base + off + (size_t)Mc * K1 * 2);

    prep_w_kernel<<<(D1 * D0 + 255) / 256, 256, 0, stream>>>(coeff1, base_w1, W1, D1 * D0);
    prep_w_kernel<<<(D2 * D1 + 255) / 256, 256, 0, stream>>>(coeff2, base_w2, W2, D2 * D1);
    prep_bias_kernel<<<D1, 256, 0, stream>>>(coeff1, bias1, b1p, D0);
    prep_bias_kernel<<<D2, 256, 0, stream>>>(coeff2, bias2, b2p, D1);

    for (int m0 = 0; m0 < B; m0 += Mc) {
        int rows = (B - m0 < Mc) ? (B - m0) : Mc;
        int nmt = rows / 256;
        expand1_kernel<<<rows, 256, 0, stream>>>(x + (size_t)m0 * D0, Xa);
        gemm8_kernel<<<nmt * (D1 / 256), 512, 0, stream>>>(
            Xa, W1, b1p, h, D1, K1, nmt);
        ln_silu_expand_kernel<<<rows, 256, 0, stream>>>(h, gamma, beta, Xa);
        gemm_kernel<<<(rows / 64) * (D2 / 128), 256, 0, stream>>>(
            Xa, W2, b2p, out + (size_t)m0 * D2, D2, K2);
    }
}